// Round 9
// baseline (85.085 us; speedup 1.0000x reference)
//
#include <hip/hip_runtime.h>
#include <hip/hip_bf16.h>

typedef __attribute__((ext_vector_type(8))) short bf16x8;   // 8 bf16 = 4 VGPRs
typedef __attribute__((ext_vector_type(4))) float f32x4;

__device__ __forceinline__ short f2bf(float v) {
    unsigned u = __builtin_bit_cast(unsigned, v);
    u += 0x7fffu + ((u >> 16) & 1u);          // round-to-nearest-even
    return (short)(u >> 16);
}
__device__ __forceinline__ float relu(float v) { return v > 0.f ? v : 0.f; }

// LDS slab: [64 ch][4 rows][64 w], row stride 68 words, ch stride 272 words.
// Pad makes acc->slab b128 writes ~2-way; drain reads are dense (8 words/bank).
#define ROWW 68
#define CHW  272                // 4*ROWW

// ---------------- prep: build bf16 W-fragments into d_ws ----------------
// Slot (mt=j*8+ot, kt, lane): lane l holds W[o = ot*16 + (l&15)][c = kt*32 + (l>>4)*8 + e].
// Same (group,elem)->k map as the X operand so the HW k-permutation cancels
// (numerically verified R1-R8).
__global__ __launch_bounds__(64)
void prep_wfrag(const float* __restrict__ w, bf16x8* __restrict__ wf) {
    const int mt   = blockIdx.x >> 2;       // 0..39
    const int kt   = blockIdx.x & 3;        // 0..3
    const int lane = threadIdx.x;           // 0..63
    const int j  = mt >> 3;
    const int ot = mt & 7;
    const int o  = ot * 16 + (lane & 15);
    const int c0 = kt * 32 + (lane >> 4) * 8;
    const float* wp = w + ((size_t)o * 128 + c0) * 5 + j;
    bf16x8 f;
    #pragma unroll
    for (int e = 0; e < 8; ++e) f[e] = f2bf(wp[e * 5]);
    wf[(size_t)(mt * 4 + kt) * 64 + lane] = f;
}

// ---------------- main: one block per (n, 4-row group) ----------------
// 8 waves: wave -> (row r = wave>>1, w-half ph = wave&1); each wave owns 2
// pos-tiles (32 positions) of its row and computes all channels (wf fragment
// loaded once per (j,ot,kt), reused for both tiles). Per tap: 2 channel-half
// phases; acc -> padded slab -> drain where ONE wave instruction = ONE
// channel's 4x64 block = 1KB fully-contiguous NT store (fill-kernel pattern).
// Shifts folded as in R7: w-shift into slab write (j=1/3, never-written edge
// column zero-filled), h-shift into store row (j=0/4, wrap row zeroed).
__global__ __launch_bounds__(512, 4)
void sconv_v9(const float* __restrict__ x, const bf16x8* __restrict__ wf,
              float* __restrict__ out) {
    __shared__ float lds[64 * CHW];         // 68 KiB

    const int bid = blockIdx.x;
    const int hq = bid & 15;                // 4-row group
    const int n  = bid >> 4;
    const int h0 = hq * 4;

    const int t    = threadIdx.x;
    const int wave = t >> 6;
    const int lane = t & 63;
    const int l15  = lane & 15;
    const int lg   = lane >> 4;
    const int r    = wave >> 1;             // row 0..3 owned by this wave
    const int ph   = wave & 1;              // which 32-wide half of the row
    const int h    = h0 + r;

    // ---- gather X fragments: 2 pos-tiles, unique per wave ----
    const float* xb = x + (size_t)n * 128 * 4096 + (size_t)(h * 64 + ph * 32 + l15);
    bf16x8 xf[2][4];
    #pragma unroll
    for (int ta = 0; ta < 2; ++ta) {
        #pragma unroll
        for (int kt = 0; kt < 4; ++kt) {
            const float* xp = xb + ta * 16 + (size_t)(kt * 32 + lg * 8) * 4096;
            bf16x8 f;
            #pragma unroll
            for (int e = 0; e < 8; ++e) f[e] = f2bf(xp[(size_t)e * 4096]);
            xf[ta][kt] = f;
        }
    }

    const int qA  = ph * 8 + lg;            // quad of tile0 acc
    const int wcA = ph * 32 + lg * 4;       // first position of tile0 acc

    #pragma unroll
    for (int j = 0; j < 5; ++j) {
        #pragma unroll
        for (int p = 0; p < 2; ++p) {
            // never-written edge column zero-fill for w-shifted taps
            if (j == 1 && t < 256) lds[(t >> 2) * CHW + (t & 3) * ROWW + 0] = 0.f;
            if (j == 3 && t < 256) lds[(t >> 2) * CHW + (t & 3) * ROWW + 63] = 0.f;

            // ---- compute + slab-write channel half p ----
            #pragma unroll
            for (int oi = 0; oi < 4; ++oi) {
                const int ot = p * 4 + oi;
                const int cl = oi * 16 + l15;   // ch within this half
                const bf16x8* wfp = wf + (size_t)((j * 8 + ot) * 4) * 64 + lane;
                f32x4 a0 = {0.f, 0.f, 0.f, 0.f};
                f32x4 a1 = {0.f, 0.f, 0.f, 0.f};
                #pragma unroll
                for (int kt = 0; kt < 4; ++kt) {
                    const bf16x8 b = wfp[(size_t)kt * 64];
                    a0 = __builtin_amdgcn_mfma_f32_16x16x32_bf16(xf[0][kt], b, a0, 0, 0, 0);
                    a1 = __builtin_amdgcn_mfma_f32_16x16x32_bf16(xf[1][kt], b, a1, 0, 0, 0);
                }

                float* const row = &lds[cl * CHW + r * ROWW];
                if (j == 0 || j == 2 || j == 4) {
                    f32x4 v0, v1;
                    #pragma unroll
                    for (int q = 0; q < 4; ++q) { v0[q] = relu(a0[q]); v1[q] = relu(a1[q]); }
                    *reinterpret_cast<f32x4*>(row + qA * 4)       = v0;
                    *reinterpret_cast<f32x4*>(row + (qA + 4) * 4) = v1;
                } else {
                    const int d = (j == 1) ? 1 : -1;
                    #pragma unroll
                    for (int q = 0; q < 4; ++q) {
                        const int w0 = wcA + q + d;
                        const int w1 = wcA + 16 + q + d;
                        if ((unsigned)w0 < 64u) row[w0] = relu(a0[q]);
                        if ((unsigned)w1 < 64u) row[w1] = relu(a1[q]);
                    }
                }
            }
            __syncthreads();

            // ---- drain: one wave instr = one channel's 4x64 = 1KB contiguous ----
            #pragma unroll
            for (int i = 0; i < 8; ++i) {
                const int cl = i * 8 + wave;    // channel within half
                const int rr = lane >> 4;       // row within group
                const int q  = lane & 15;       // quad within row
                f32x4 v = *reinterpret_cast<const f32x4*>(
                    &lds[cl * CHW + rr * ROWW + q * 4]);
                const int hh = h0 + rr;
                const int hs = (j == 0) ? ((hh + 1) & 63)
                             : (j == 4) ? ((hh + 63) & 63) : hh;
                if ((j == 0 && hh == 63) || (j == 4 && hh == 0))
                    v = f32x4{0.f, 0.f, 0.f, 0.f};
                __builtin_nontemporal_store(
                    v, reinterpret_cast<f32x4*>(
                           out + (((size_t)n * 640 + j * 128 + p * 64 + cl) * 64
                                  + hs) * 64 + q * 4));
            }
            if (j < 4 || p < 1) __syncthreads();
        }
    }
}

// ---------------- fallback (R1 kernel) if workspace is too small ----------------
__global__ __launch_bounds__(512, 2)
void sconv_mfma(const float* __restrict__ x, const float* __restrict__ w,
                float* __restrict__ out) {
    __shared__ bf16x8 wfrag[8][4][64];
    const int bid = blockIdx.x;
    const int j   = bid % 5;
    const int hp  = (bid / 5) % 32;
    const int n   = bid / 160;
    const int t = threadIdx.x;
    for (int s = t; s < 2048; s += 512) {
        const int lane = s & 63;
        const int rest = s >> 6;
        const int mt   = rest >> 2;
        const int kt   = rest & 3;
        const int o    = mt * 16 + (lane & 15);
        const int c0   = kt * 32 + (lane >> 4) * 8;
        const float* wp = w + ((size_t)o * 128 + c0) * 5 + j;
        bf16x8 f;
        #pragma unroll
        for (int e = 0; e < 8; ++e) f[e] = f2bf(wp[e * 5]);
        wfrag[mt][kt][lane] = f;
    }
    __syncthreads();
    const int wave = t >> 6;
    const int lane = t & 63;
    const int l15  = lane & 15;
    const int lg   = lane >> 4;
    const int h    = hp * 2 + (wave >> 2);
    const int wcol = (wave & 3) * 16 + l15;
    const int dy[5] = {-1, 0, 0, 0, 1};
    const int dx[5] = { 0,-1, 0, 1, 0};
    const int hi = h + dy[j];
    const int wi = wcol + dx[j];
    const bool valid = ((unsigned)hi < 64u) && ((unsigned)wi < 64u);
    const int hic = hi < 0 ? 0 : (hi > 63 ? 63 : hi);
    const int wic = wi < 0 ? 0 : (wi > 63 ? 63 : wi);
    const float* xb = x + (size_t)n * 128 * 4096 + (size_t)(hic * 64 + wic);
    bf16x8 xf[4];
    #pragma unroll
    for (int kt = 0; kt < 4; ++kt) {
        const int c0 = kt * 32 + lg * 8;
        const float* xp = xb + (size_t)c0 * 4096;
        bf16x8 f;
        #pragma unroll
        for (int e = 0; e < 8; ++e) {
            float v = xp[(size_t)e * 4096];
            f[e] = f2bf(valid ? v : 0.0f);
        }
        xf[kt] = f;
    }
    f32x4 acc[8];
    #pragma unroll
    for (int mt = 0; mt < 8; ++mt) acc[mt] = f32x4{0.f, 0.f, 0.f, 0.f};
    #pragma unroll
    for (int kt = 0; kt < 4; ++kt)
        #pragma unroll
        for (int mt = 0; mt < 8; ++mt)
            acc[mt] = __builtin_amdgcn_mfma_f32_16x16x32_bf16(
                wfrag[mt][kt][lane], xf[kt], acc[mt], 0, 0, 0);
    float* ob = out + ((size_t)n * 640 + (size_t)j * 128) * 4096
                    + (size_t)(h * 64 + wcol);
    #pragma unroll
    for (int mt = 0; mt < 8; ++mt) {
        const int ch = mt * 16 + lg * 4;
        #pragma unroll
        for (int r = 0; r < 4; ++r) {
            float v = acc[mt][r];
            ob[(size_t)(ch + r) * 4096] = v > 0.f ? v : 0.f;
        }
    }
}

extern "C" void kernel_launch(void* const* d_in, const int* in_sizes, int n_in,
                              void* d_out, int out_size, void* d_ws, size_t ws_size,
                              hipStream_t stream) {
    const float* x = (const float*)d_in[0];   // [32,128,64,64] f32
    const float* w = (const float*)d_in[1];   // [128,128,5] f32
    float* out = (float*)d_out;               // [32,640,64,64] f32

    const size_t wf_bytes = (size_t)40 * 4 * 64 * sizeof(bf16x8);  // 160 KiB
    if (ws_size >= wf_bytes) {
        bf16x8* wf = (bf16x8*)d_ws;
        hipLaunchKernelGGL(prep_wfrag, dim3(160), dim3(64), 0, stream, w, wf);
        hipLaunchKernelGGL(sconv_v9, dim3(32 * 16), dim3(512), 0, stream,
                           x, wf, out);
    } else {
        hipLaunchKernelGGL(sconv_mfma, dim3(32 * 32 * 5), dim3(512), 0, stream,
                           x, w, out);
    }
}

// Round 10
// 82.096 us; speedup vs baseline: 1.0364x; 1.0364x over previous
//
#include <hip/hip_runtime.h>
#include <hip/hip_bf16.h>

typedef __attribute__((ext_vector_type(8))) short bf16x8;   // 8 bf16 = 4 VGPRs
typedef __attribute__((ext_vector_type(4))) float f32x4;

__device__ __forceinline__ short f2bf(float v) {
    unsigned u = __builtin_bit_cast(unsigned, v);
    u += 0x7fffu + ((u >> 16) & 1u);          // round-to-nearest-even
    return (short)(u >> 16);
}
__device__ __forceinline__ float relu(float v) { return v > 0.f ? v : 0.f; }

// Slab geometry (per v7, verified): [64 ch][2 rows][64 w], +4-float row pad.
#define ROWP 68                 // floats per (ch,row) row
#define CHP  136                // floats per ch (2 rows)

// ---------------- prep: build bf16 W-fragments into d_ws ----------------
// Slot (mt=j*8+ot, kt, lane): lane l holds W[o = ot*16 + (l&15)][c = kt*32 + (l>>4)*8 + e].
// Same (group,elem)->k map as the X operand so the HW k-permutation cancels
// (numerically verified R1-R9).
__global__ __launch_bounds__(64)
void prep_wfrag(const float* __restrict__ w, bf16x8* __restrict__ wf) {
    const int mt   = blockIdx.x >> 2;       // 0..39
    const int kt   = blockIdx.x & 3;        // 0..3
    const int lane = threadIdx.x;           // 0..63
    const int j  = mt >> 3;
    const int ot = mt & 7;
    const int o  = ot * 16 + (lane & 15);
    const int c0 = kt * 32 + (lane >> 4) * 8;
    const float* wp = w + ((size_t)o * 128 + c0) * 5 + j;
    bf16x8 f;
    #pragma unroll
    for (int e = 0; e < 8; ++e) f[e] = f2bf(wp[e * 5]);
    wf[(size_t)(mt * 4 + kt) * 64 + lane] = f;
}

// ---------------- main: one block per (n, row-pair), 2-slab pipeline ----------------
// v7 compute/drain/shift logic, restructured as a 10-region software pipeline:
// region k: { drain slab[k-1] (all waves)  ||  compute phase k -> slab[k&1]
// (waves mh==p) } ; ONE barrier per region (10 total vs v7's 20). Slabs
// alternate p=0 -> lds[0], p=1 -> lds[1]; drain always reads the other slab.
__global__ __launch_bounds__(512, 4)
void sconv_v10(const float* __restrict__ x, const bf16x8* __restrict__ wf,
               float* __restrict__ out) {
    __shared__ float lds[2][64 * CHP];      // 2 x 34 KiB

    const int bid = blockIdx.x;
    const int hp = bid & 31;                // row pair index
    const int n  = bid >> 5;
    const int h0 = hp * 2;

    const int t    = threadIdx.x;
    const int wave = t >> 6;
    const int lane = t & 63;
    const int mh   = wave >> 2;             // channel half owned by this wave
    const int pt   = wave & 3;              // 16-wide position tile
    const int l15  = lane & 15;
    const int lg   = lane >> 4;
    const int pos  = pt * 16 + l15;         // gather position (A row map)

    // ---- gather X fragments for both rows, kept in regs (v7-identical) ----
    const float* xb = x + (size_t)n * 128 * 4096 + (size_t)(h0 * 64 + pos);
    bf16x8 xf[2][4];
    #pragma unroll
    for (int r = 0; r < 2; ++r) {
        #pragma unroll
        for (int kt = 0; kt < 4; ++kt) {
            const float* xp = xb + (size_t)r * 64
                            + (size_t)(kt * 32 + lg * 8) * 4096;
            bf16x8 f;
            #pragma unroll
            for (int e = 0; e < 8; ++e) f[e] = f2bf(xp[(size_t)e * 4096]);
            xf[r][kt] = f;
        }
    }

    const int wq  = pt * 4 + lg;            // quad this lane's acc covers
    const int wp0 = pt * 16 + lg * 4;       // first position of that quad

// compute channel-half P of tap J into slab lds[P] (waves mh==P only),
// plus edge-column zero-fill for w-shifted taps. v7-verified logic.
#define PHASE_C(J, P)                                                         \
    {                                                                         \
        if ((J) == 1 && t < 128)                                              \
            lds[P][(t >> 1) * CHP + (t & 1) * ROWP + 0] = 0.f;                \
        if ((J) == 3 && t < 128)                                              \
            lds[P][(t >> 1) * CHP + (t & 1) * ROWP + 63] = 0.f;               \
        if (mh == (P)) {                                                      \
            _Pragma("unroll")                                                 \
            for (int oi = 0; oi < 4; ++oi) {                                  \
                const int ot = (P) * 4 + oi;                                  \
                const int cl = oi * 16 + l15;                                 \
                const bf16x8* wfp =                                           \
                    wf + (size_t)(((J) * 8 + ot) * 4) * 64 + lane;            \
                f32x4 a0 = {0.f, 0.f, 0.f, 0.f};                              \
                f32x4 a1 = {0.f, 0.f, 0.f, 0.f};                              \
                _Pragma("unroll")                                             \
                for (int kt = 0; kt < 4; ++kt) {                              \
                    const bf16x8 b = wfp[(size_t)kt * 64];                    \
                    a0 = __builtin_amdgcn_mfma_f32_16x16x32_bf16(             \
                        xf[0][kt], b, a0, 0, 0, 0);                           \
                    a1 = __builtin_amdgcn_mfma_f32_16x16x32_bf16(             \
                        xf[1][kt], b, a1, 0, 0, 0);                           \
                }                                                             \
                float* const row0 = &lds[P][cl * CHP];                        \
                if ((J) == 0 || (J) == 2 || (J) == 4) {                       \
                    f32x4 v0, v1;                                             \
                    _Pragma("unroll")                                         \
                    for (int q = 0; q < 4; ++q) {                             \
                        v0[q] = relu(a0[q]); v1[q] = relu(a1[q]);             \
                    }                                                         \
                    *reinterpret_cast<f32x4*>(row0 + wq * 4) = v0;            \
                    *reinterpret_cast<f32x4*>(row0 + ROWP + wq * 4) = v1;     \
                } else {                                                      \
                    const int d = ((J) == 1) ? 1 : -1;                        \
                    _Pragma("unroll")                                         \
                    for (int q = 0; q < 4; ++q) {                             \
                        const int ws = wp0 + q + d;                           \
                        if ((unsigned)ws < 64u) {                             \
                            row0[ws] = relu(a0[q]);                          \
                            row0[ROWP + ws] = relu(a1[q]);                   \
                        }                                                     \
                    }                                                         \
                }                                                             \
            }                                                                 \
        }                                                                     \
    }

// drain slab lds[P] for (J,P): 512B-contiguous NT dwordx4 (v7-verified).
#define PHASE_D(J, P)                                                         \
    {                                                                         \
        _Pragma("unroll")                                                     \
        for (int i = 0; i < 4; ++i) {                                         \
            const int g  = i * 512 + t;                                       \
            const int cl = g >> 5;                                            \
            const int hr = (g >> 4) & 1;                                      \
            const int q  = g & 15;                                            \
            f32x4 v = *reinterpret_cast<const f32x4*>(                        \
                &lds[P][cl * CHP + hr * ROWP + q * 4]);                       \
            const int hh = h0 + hr;                                           \
            const int hs = ((J) == 0) ? ((hh + 1) & 63)                       \
                         : ((J) == 4) ? ((hh + 63) & 63) : hh;                \
            if (((J) == 0 && hh == 63) || ((J) == 4 && hh == 0))              \
                v = f32x4{0.f, 0.f, 0.f, 0.f};                                \
            __builtin_nontemporal_store(                                      \
                v, reinterpret_cast<f32x4*>(                                  \
                       out + (((size_t)n * 640 + (J) * 128 + (P) * 64 + cl)   \
                              * 64 + hs) * 64 + q * 4));                      \
        }                                                                     \
    }

    PHASE_C(0, 0); __syncthreads();
    PHASE_D(0, 0); PHASE_C(0, 1); __syncthreads();
    PHASE_D(0, 1); PHASE_C(1, 0); __syncthreads();
    PHASE_D(1, 0); PHASE_C(1, 1); __syncthreads();
    PHASE_D(1, 1); PHASE_C(2, 0); __syncthreads();
    PHASE_D(2, 0); PHASE_C(2, 1); __syncthreads();
    PHASE_D(2, 1); PHASE_C(3, 0); __syncthreads();
    PHASE_D(3, 0); PHASE_C(3, 1); __syncthreads();
    PHASE_D(3, 1); PHASE_C(4, 0); __syncthreads();
    PHASE_D(4, 0); PHASE_C(4, 1); __syncthreads();
    PHASE_D(4, 1);

#undef PHASE_C
#undef PHASE_D
}

// ---------------- fallback (R1 kernel) if workspace is too small ----------------
__global__ __launch_bounds__(512, 2)
void sconv_mfma(const float* __restrict__ x, const float* __restrict__ w,
                float* __restrict__ out) {
    __shared__ bf16x8 wfrag[8][4][64];
    const int bid = blockIdx.x;
    const int j   = bid % 5;
    const int hp  = (bid / 5) % 32;
    const int n   = bid / 160;
    const int t = threadIdx.x;
    for (int s = t; s < 2048; s += 512) {
        const int lane = s & 63;
        const int rest = s >> 6;
        const int mt   = rest >> 2;
        const int kt   = rest & 3;
        const int o    = mt * 16 + (lane & 15);
        const int c0   = kt * 32 + (lane >> 4) * 8;
        const float* wp = w + ((size_t)o * 128 + c0) * 5 + j;
        bf16x8 f;
        #pragma unroll
        for (int e = 0; e < 8; ++e) f[e] = f2bf(wp[e * 5]);
        wfrag[mt][kt][lane] = f;
    }
    __syncthreads();
    const int wave = t >> 6;
    const int lane = t & 63;
    const int l15  = lane & 15;
    const int lg   = lane >> 4;
    const int h    = hp * 2 + (wave >> 2);
    const int wcol = (wave & 3) * 16 + l15;
    const int dy[5] = {-1, 0, 0, 0, 1};
    const int dx[5] = { 0,-1, 0, 1, 0};
    const int hi = h + dy[j];
    const int wi = wcol + dx[j];
    const bool valid = ((unsigned)hi < 64u) && ((unsigned)wi < 64u);
    const int hic = hi < 0 ? 0 : (hi > 63 ? 63 : hi);
    const int wic = wi < 0 ? 0 : (wi > 63 ? 63 : wi);
    const float* xb = x + (size_t)n * 128 * 4096 + (size_t)(hic * 64 + wic);
    bf16x8 xf[4];
    #pragma unroll
    for (int kt = 0; kt < 4; ++kt) {
        const int c0 = kt * 32 + lg * 8;
        const float* xp = xb + (size_t)c0 * 4096;
        bf16x8 f;
        #pragma unroll
        for (int e = 0; e < 8; ++e) {
            float v = xp[(size_t)e * 4096];
            f[e] = f2bf(valid ? v : 0.0f);
        }
        xf[kt] = f;
    }
    f32x4 acc[8];
    #pragma unroll
    for (int mt = 0; mt < 8; ++mt) acc[mt] = f32x4{0.f, 0.f, 0.f, 0.f};
    #pragma unroll
    for (int kt = 0; kt < 4; ++kt)
        #pragma unroll
        for (int mt = 0; mt < 8; ++mt)
            acc[mt] = __builtin_amdgcn_mfma_f32_16x16x32_bf16(
                wfrag[mt][kt][lane], xf[kt], acc[mt], 0, 0, 0);
    float* ob = out + ((size_t)n * 640 + (size_t)j * 128) * 4096
                    + (size_t)(h * 64 + wcol);
    #pragma unroll
    for (int mt = 0; mt < 8; ++mt) {
        const int ch = mt * 16 + lg * 4;
        #pragma unroll
        for (int r = 0; r < 4; ++r) {
            float v = acc[mt][r];
            ob[(size_t)(ch + r) * 4096] = v > 0.f ? v : 0.f;
        }
    }
}

extern "C" void kernel_launch(void* const* d_in, const int* in_sizes, int n_in,
                              void* d_out, int out_size, void* d_ws, size_t ws_size,
                              hipStream_t stream) {
    const float* x = (const float*)d_in[0];   // [32,128,64,64] f32
    const float* w = (const float*)d_in[1];   // [128,128,5] f32
    float* out = (float*)d_out;               // [32,640,64,64] f32

    const size_t wf_bytes = (size_t)40 * 4 * 64 * sizeof(bf16x8);  // 160 KiB
    if (ws_size >= wf_bytes) {
        bf16x8* wf = (bf16x8*)d_ws;
        hipLaunchKernelGGL(prep_wfrag, dim3(160), dim3(64), 0, stream, w, wf);
        hipLaunchKernelGGL(sconv_v10, dim3(32 * 32), dim3(512), 0, stream,
                           x, wf, out);
    } else {
        hipLaunchKernelGGL(sconv_mfma, dim3(32 * 32 * 5), dim3(512), 0, stream,
                           x, w, out);
    }
}